// Round 3
// baseline (110.832 us; speedup 1.0000x reference)
//
#include <hip/hip_runtime.h>
#include <math.h>

// Problem constants (match reference)
#define BB   16      // batch
#define HH   16      // heads
#define DD   128     // head dim
#define BLK  16      // tokens per cache block
#define BPS  128     // blocks per sequence
#define SS   2048    // max context (BPS*BLK)
#define SCALE_F 0.08838834764831845f

#define SPLIT 32
#define CHK   (SS / SPLIT)   // 64 tokens per block
#define NT1   512
#define NW1   8              // waves per block
#define TPW   (CHK / NW1)    // 8 tokens per wave

// ---------------- kernel 1: per-(b,chunk) partial attention, ALL heads ----------------
// A wave reads whole 8KB token rows contiguously (all 16 heads at once).
// Lane l in pass p holds head 2p+(l>>5), dims (l&31)*4 .. +4.
__global__ __launch_bounds__(NT1, 2)
void pd_partial(const float* __restrict__ q,
                const float* __restrict__ knew,
                const float* __restrict__ vnew,
                const float* __restrict__ kc,
                const float* __restrict__ vc,
                const int*   __restrict__ bt,
                const int*   __restrict__ smap_g,
                const int*   __restrict__ clen,
                float*       __restrict__ ml,
                float*       __restrict__ pacc)
{
    __shared__ float red[4 * 2048];   // 32 KB tree-reduce buffer (4 waves x 8KB)
    __shared__ float sc[HH * CHK];    // scores [h][tok], 4 KB
    __shared__ int   rbs[CHK];        // per-token row base (floats) or -(j+1)
    __shared__ int   smap[BB];

    const int bid  = blockIdx.x;
    const int c    = bid & (SPLIT - 1);
    const int b    = bid >> 5;        // SPLIT == 32
    const int t    = threadIdx.x;
    const int lane = t & 63;
    const int w    = t >> 6;
    const int hh   = lane >> 5;       // which head-half of the pass
    const int d4   = lane & 31;       // dim-quad within head
    const int len  = clen[b];
    const int sbase = c * CHK;

    if (t < BB) smap[t] = smap_g[t];
    __syncthreads();

    if (t < CHK) {
        int s    = sbase + t;
        int pb   = bt[b * BPS + (s >> 4)];
        int slot = pb * BLK + (s & 15);
        int enc  = slot * (HH * DD);            // float offset of the full token row
        #pragma unroll
        for (int j = 0; j < BB; ++j)
            if (slot == smap[j]) enc = -(j + 1);
        rbs[t] = enc;
    }
    __syncthreads();

    // per-lane q fragments: pass p needs q[b][2p+hh][d4*4 .. +4]
    float4 qf[8];
    #pragma unroll
    for (int p = 0; p < 8; ++p)
        qf[p] = *(const float4*)(q + b * (HH * DD) + (2 * p + hh) * DD + d4 * 4);

    // ---- phase 1: scores (contiguous 8KB row reads) ----
    #pragma unroll
    for (int i = 0; i < TPW; ++i) {
        int tok = w + NW1 * i;
        int enc = rbs[tok];
        const float* rp = (enc >= 0) ? (kc + enc) : (knew + (-enc - 1) * (HH * DD));
        #pragma unroll
        for (int p = 0; p < 8; ++p) {
            float4 kv = *(const float4*)(rp + p * 256 + lane * 4);
            float d = qf[p].x * kv.x + qf[p].y * kv.y + qf[p].z * kv.z + qf[p].w * kv.w;
            d += __shfl_xor(d, 1);
            d += __shfl_xor(d, 2);
            d += __shfl_xor(d, 4);
            d += __shfl_xor(d, 8);
            d += __shfl_xor(d, 16);
            if (d4 == 0) sc[(2 * p + hh) * CHK + tok] = d * SCALE_F;
        }
    }
    __syncthreads();

    // ---- phase 2: per-head softmax (wave w -> heads 2w, 2w+1) ----
    {
        int h = 2 * w + hh;
        int t0 = d4, t1 = d4 + 32;
        float v0 = (sbase + t0 < len) ? sc[h * CHK + t0] : -1e30f;
        float v1 = (sbase + t1 < len) ? sc[h * CHK + t1] : -1e30f;
        float m = fmaxf(v0, v1);
        #pragma unroll
        for (int msk = 16; msk >= 1; msk >>= 1)
            m = fmaxf(m, __shfl_xor(m, msk));
        float e0 = expf(v0 - m), e1 = expf(v1 - m);
        float sum = e0 + e1;
        #pragma unroll
        for (int msk = 16; msk >= 1; msk >>= 1)
            sum += __shfl_xor(sum, msk);
        sc[h * CHK + t0] = e0;
        sc[h * CHK + t1] = e1;
        if (d4 == 0) {
            ml[((b * HH + h) * SPLIT + c) * 2]     = m;
            ml[((b * HH + h) * SPLIT + c) * 2 + 1] = sum;
        }
    }
    __syncthreads();

    // ---- phase 3: PV (contiguous 8KB row reads, 8 per-lane accumulators) ----
    float4 acc[8];
    #pragma unroll
    for (int p = 0; p < 8; ++p) acc[p] = make_float4(0.f, 0.f, 0.f, 0.f);

    #pragma unroll
    for (int i = 0; i < TPW; ++i) {
        int tok = w + NW1 * i;
        int enc = rbs[tok];
        const float* rp = (enc >= 0) ? (vc + enc) : (vnew + (-enc - 1) * (HH * DD));
        #pragma unroll
        for (int p = 0; p < 8; ++p) {
            float4 vv = *(const float4*)(rp + p * 256 + lane * 4);
            float pr = sc[(2 * p + hh) * CHK + tok];
            acc[p].x += pr * vv.x;
            acc[p].y += pr * vv.y;
            acc[p].z += pr * vv.z;
            acc[p].w += pr * vv.w;
        }
    }

    // ---- cross-wave tree reduce (8 -> 1) ----
    #pragma unroll
    for (int r = 4; r >= 1; r >>= 1) {
        if (w >= r && w < 2 * r) {
            #pragma unroll
            for (int p = 0; p < 8; ++p)
                *(float4*)&red[(w - r) * 2048 + p * 256 + lane * 4] = acc[p];
        }
        __syncthreads();
        if (w < r) {
            #pragma unroll
            for (int p = 0; p < 8; ++p) {
                float4 o = *(const float4*)&red[w * 2048 + p * 256 + lane * 4];
                acc[p].x += o.x; acc[p].y += o.y; acc[p].z += o.z; acc[p].w += o.w;
            }
        }
        __syncthreads();
    }

    if (w == 0) {
        #pragma unroll
        for (int p = 0; p < 8; ++p) {
            int h = 2 * p + hh;
            *(float4*)&pacc[((b * HH + h) * SPLIT + c) * DD + d4 * 4] = acc[p];
        }
    }
}

// ---------------- kernel 2: online LSE merge of SPLIT partials per (b,h) ----------------
__global__ __launch_bounds__(DD)
void pd_combine(const float* __restrict__ ml,
                const float* __restrict__ pacc,
                float*       __restrict__ out)
{
    const int bh = blockIdx.x;
    const int t  = threadIdx.x;  // 0..127

    float M = -1e30f, den = 0.f, o = 0.f;
    #pragma unroll 8
    for (int i = 0; i < SPLIT; ++i) {
        float mi = ml[(bh * SPLIT + i) * 2];
        float li = ml[(bh * SPLIT + i) * 2 + 1];
        float nm = fmaxf(M, mi);
        float sOld = expf(M - nm);
        float sNew = expf(mi - nm);
        o   = o * sOld + sNew * pacc[(bh * SPLIT + i) * DD + t];
        den = den * sOld + sNew * li;
        M = nm;
    }
    out[bh * DD + t] = o / den;
}

extern "C" void kernel_launch(void* const* d_in, const int* in_sizes, int n_in,
                              void* d_out, int out_size, void* d_ws, size_t ws_size,
                              hipStream_t stream)
{
    const float* q    = (const float*)d_in[0];
    const float* knew = (const float*)d_in[1];
    const float* vnew = (const float*)d_in[2];
    const float* kc   = (const float*)d_in[3];
    const float* vc   = (const float*)d_in[4];
    const int*   bt   = (const int*)d_in[5];
    const int*   smap = (const int*)d_in[6];
    const int*   clen = (const int*)d_in[7];
    float*       out  = (float*)d_out;

    float* ml   = (float*)d_ws;                        // [B*H*SPLIT][2]  = 64 KB
    float* pacc = (float*)d_ws + BB * HH * SPLIT * 2;  // [B*H*SPLIT][DD] = 4 MB

    pd_partial<<<dim3(BB * SPLIT), dim3(NT1), 0, stream>>>(
        q, knew, vnew, kc, vc, bt, smap, clen, ml, pacc);
    pd_combine<<<dim3(BB * HH), dim3(DD), 0, stream>>>(ml, pacc, out);
}